// Round 10
// baseline (556.978 us; speedup 1.0000x reference)
//
#include <hip/hip_runtime.h>
#include <math.h>

#define BATCH 8192
#define FEAT  256
#define NCLS  1000

#define REPL    2                    // replicas per class, SAME-XCD pairing
#define NINTRA  (REPL*NCLS)          // 2000 intra blocks, dispatched FIRST
#define NGEMM   528                  // upper-tri 32x32 grid of 32x32 tiles
#define NBLK    (NINTRA + NGEMM)     // 2528
#define ROWCAP  24                   // rows staged in LDS per class
#define MEMCAP  96                   // hard cap on class size

// ws (f32): [0,2000)      per-intra-block max  (plain store, no init needed)
//           [2000,2528)   per-GEMM-block min   (plain store, no init needed)
// Every slot unconditionally written every call -> harness 0xAA poison harmless.

// LDS union:
//   intra: rowS[24][256] 24576 | mem[96] 384 | magS[96] 384          = 25344 B
//   GEMM : As[32][34] 4352 | Bs[32][34] 4352 | cmagI[32] | cmagJ[32] =  8960 B
__global__ __launch_bounds__(256) void k_main(const float* __restrict__ x,
                                              const int* __restrict__ labels,
                                              const float* __restrict__ centers,
                                              float* __restrict__ ws) {
    __shared__ __align__(16) char raw[25408];
    __shared__ float wred[4];
    __shared__ int cnt;
    int t = threadIdx.x;
    int lane = t & 63, w = t >> 6;

    if (blockIdx.x < NINTRA) {
        // ---- intra: class-owned replicas; bid c and 1000+c share an XCD ----
        int bid = blockIdx.x;
        int c   = (bid < NCLS) ? bid : bid - NCLS;   // class id
        int r   = (bid < NCLS) ? 0 : 1;              // replica id
        float (*rowS)[256] = reinterpret_cast<float(*)[256]>(raw);
        int*   mem  = reinterpret_cast<int*>(raw + 24576);
        float* magS = reinterpret_cast<float*>(raw + 24960);

        if (t == 0) cnt = 0;
        __syncthreads();
        // find members: coalesced int4 scan of labels (L2-resident, 32KB)
        const int4* gl4 = reinterpret_cast<const int4*>(labels);
        #pragma unroll
        for (int k = 0; k < 8; ++k) {
            int4 lv = gl4[t + (k << 8)];
            int base = (t + (k << 8)) << 2;
            if (lv.x == c) { int p = atomicAdd(&cnt, 1); if (p < MEMCAP) mem[p] = base;     }
            if (lv.y == c) { int p = atomicAdd(&cnt, 1); if (p < MEMCAP) mem[p] = base + 1; }
            if (lv.z == c) { int p = atomicAdd(&cnt, 1); if (p < MEMCAP) mem[p] = base + 2; }
            if (lv.w == c) { int p = atomicAdd(&cnt, 1); if (p < MEMCAP) mem[p] = base + 3; }
        }
        __syncthreads();
        int n = cnt < MEMCAP ? cnt : MEMCAP;
        float vmax = 0.0f;
        if (n >= 2) {
            const float4* x4 = reinterpret_cast<const float4*>(x);
            // batched staging: issue all (<=6) row loads back-to-back, THEN reduce.
            float4 vb[6];
            #pragma unroll
            for (int q = 0; q < 6; ++q) {
                int m = w + q * 4;
                vb[q] = (m < n) ? x4[(size_t)mem[m] * 64 + lane]
                                : make_float4(0.f, 0.f, 0.f, 0.f);
            }
            #pragma unroll
            for (int q = 0; q < 6; ++q) {
                int m = w + q * 4;
                if (m < n) {
                    float4 v = vb[q];
                    *reinterpret_cast<float4*>(&rowS[m][lane << 2]) = v;  // m<24 always here
                    float s = v.x * v.x + v.y * v.y + v.z * v.z + v.w * v.w;
                    #pragma unroll
                    for (int o = 32; o > 0; o >>= 1) s += __shfl_xor(s, o);
                    if (lane == 0) magS[m] = s;
                }
            }
            // correctness fallback for n>24 (essentially never): mags only
            for (int m = ROWCAP + w; m < n; m += 4) {
                float4 v = x4[(size_t)mem[m] * 64 + lane];
                float s = v.x * v.x + v.y * v.y + v.z * v.z + v.w * v.w;
                #pragma unroll
                for (int o = 32; o > 0; o >>= 1) s += __shfl_xor(s, o);
                if (lane == 0) magS[m] = s;
            }
            __syncthreads();
            int npairs = n * (n - 1) / 2;
            for (int p = r * 4 + w; p < npairs; p += 8) {    // residue-unique pairs
                int a = 0, rem = p;                           // unrank (a-major)
                while (rem >= n - 1 - a) { rem -= n - 1 - a; ++a; }
                int b = a + 1 + rem;
                float4 va = (a < ROWCAP)
                    ? *reinterpret_cast<float4*>(&rowS[a][lane << 2])
                    : x4[(size_t)mem[a] * 64 + lane];
                float4 vb2 = (b < ROWCAP)
                    ? *reinterpret_cast<float4*>(&rowS[b][lane << 2])
                    : x4[(size_t)mem[b] * 64 + lane];
                float s = va.x * vb2.x + va.y * vb2.y + va.z * vb2.z + va.w * vb2.w;
                #pragma unroll
                for (int o = 32; o > 0; o >>= 1) s += __shfl_xor(s, o);
                float d2 = magS[a] + magS[b] - 2.0f * s;     // add commutes: bit-same
                float d  = sqrtf(fmaxf(d2, 0.0f));
                d = fminf(fmaxf(d, 1e-12f), 1e12f);
                vmax = fmaxf(vmax, d);
            }
        }
        if (lane == 0) wred[w] = vmax;
        __syncthreads();
        if (t == 0) {
            float m = fmaxf(fmaxf(wred[0], wred[1]), fmaxf(wred[2], wred[3]));
            ws[bid] = m;                                // plain store, unique slot
        }
    } else {
        // ------- inter: upper-tri 32x32 tile, k-major LDS, 2x2 reg tile,
        //         register double-buffered global loads (issue-early) -------
        float (*As)[34] = reinterpret_cast<float(*)[34]>(raw);
        float (*Bs)[34] = reinterpret_cast<float(*)[34]>(raw + 4352);
        float* cmagI    = reinterpret_cast<float*>(raw + 8704);
        float* cmagJ    = reinterpret_cast<float*>(raw + 8832);

        int bi = 0, rem = blockIdx.x - NINTRA;      // unrank upper-tri 32x32 grid
        while (rem >= 32 - bi) { rem -= 32 - bi; ++bi; }
        int bj = bi + rem;
        int i0 = bi * 32, j0 = bj * 32;

        // cmag for both row-ranges (bit-exact rownorm tree, I/J interleaved)
        for (int q = w; q < 32; q += 4) {
            int gi = i0 + q, gj = j0 + q;
            float sI = 0.0f, sJ = 0.0f;
            if (gi < NCLS) {
                float4 v = reinterpret_cast<const float4*>(centers + (size_t)gi * FEAT)[lane];
                sI = v.x * v.x + v.y * v.y + v.z * v.z + v.w * v.w;
            }
            if (gj < NCLS) {
                float4 v = reinterpret_cast<const float4*>(centers + (size_t)gj * FEAT)[lane];
                sJ = v.x * v.x + v.y * v.y + v.z * v.z + v.w * v.w;
            }
            #pragma unroll
            for (int o = 32; o > 0; o >>= 1) {
                sI += __shfl_xor(sI, o);
                sJ += __shfl_xor(sJ, o);
            }
            if (lane == 0) { cmagI[q] = 2.0f * sI; cmagJ[q] = 2.0f * sJ; }
        }
        // (k-loop barriers below order cmag writes before the epilogue reads)

        int row = t >> 3, q = t & 7;                // staging coords
        int gi = i0 + row, gj = j0 + row;
        bool vi = gi < NCLS, vj = gj < NCLS;
        const float4* pgi = reinterpret_cast<const float4*>(centers + (size_t)gi * FEAT) + q;
        const float4* pgj = reinterpret_cast<const float4*>(centers + (size_t)gj * FEAT) + q;
        float4 zero = make_float4(0.f, 0.f, 0.f, 0.f);
        float4 av = vi ? pgi[0] : zero;             // prefetch chunk 0
        float4 bv = vj ? pgj[0] : zero;

        int tx = t & 15, ty = t >> 4;               // 2 cols, 2 rows per thread
        float acc[2][2] = {{0.f, 0.f}, {0.f, 0.f}};
        #pragma unroll
        for (int kc = 0; kc < 8; ++kc) {            // 8 chunks of 32 k
            As[q * 4 + 0][row] = av.x; As[q * 4 + 1][row] = av.y;
            As[q * 4 + 2][row] = av.z; As[q * 4 + 3][row] = av.w;
            Bs[q * 4 + 0][row] = bv.x; Bs[q * 4 + 1][row] = bv.y;
            Bs[q * 4 + 2][row] = bv.z; Bs[q * 4 + 3][row] = bv.w;
            float4 av_n = zero, bv_n = zero;
            if (kc < 7) {                            // issue next loads EARLY
                av_n = vi ? pgi[(kc + 1) * 8] : zero;
                bv_n = vj ? pgj[(kc + 1) * 8] : zero;
            }
            __syncthreads();
            #pragma unroll
            for (int k = 0; k < 32; ++k) {          // k strictly sequential per acc
                float2 a2 = *reinterpret_cast<float2*>(&As[k][ty * 2]);
                float2 b2 = *reinterpret_cast<float2*>(&Bs[k][tx * 2]);
                acc[0][0] += a2.x * b2.x; acc[0][1] += a2.x * b2.y;
                acc[1][0] += a2.y * b2.x; acc[1][1] += a2.y * b2.y;
            }
            __syncthreads();
            av = av_n; bv = bv_n;
        }
        float lmin = 1e30f;
        #pragma unroll
        for (int jj = 0; jj < 2; ++jj) {
            int J = j0 + tx * 2 + jj;
            #pragma unroll
            for (int ii = 0; ii < 2; ++ii) {
                int I = i0 + ty * 2 + ii;
                if (I < NCLS && J < NCLS) {
                    float v1 = cmagJ[tx * 2 + jj] - 2.0f * acc[ii][jj];   // entry (I,J)
                    v1 = fminf(fmaxf(v1, 1e-12f), 1e12f);
                    float v2 = cmagI[ty * 2 + ii] - 2.0f * acc[ii][jj];   // entry (J,I)
                    v2 = fminf(fmaxf(v2, 1e-12f), 1e12f);
                    lmin = fminf(lmin, fminf(v1, v2));
                }
            }
        }
        #pragma unroll
        for (int o = 32; o > 0; o >>= 1) lmin = fminf(lmin, __shfl_xor(lmin, o));
        if (lane == 0) wred[w] = lmin;
        __syncthreads();
        if (t == 0) {
            float m = fminf(fminf(wred[0], wred[1]), fminf(wred[2], wred[3]));
            ws[blockIdx.x] = m;                         // plain store, unique slot
        }
    }
}

// One block, 256 threads: reduce the per-block partials, write the scalar.
__global__ __launch_bounds__(256) void k_final(const float* __restrict__ ws,
                                               float* __restrict__ out) {
    __shared__ float smx[4], smn[4];
    int t = threadIdx.x, lane = t & 63, w = t >> 6;
    float mn = 1e30f, mx = 0.0f;
    for (int i = t; i < NINTRA; i += 256) mx = fmaxf(mx, ws[i]);
    for (int i = t; i < NGEMM; i += 256)  mn = fminf(mn, ws[NINTRA + i]);
    #pragma unroll
    for (int o = 32; o > 0; o >>= 1) {
        mx = fmaxf(mx, __shfl_xor(mx, o));
        mn = fminf(mn, __shfl_xor(mn, o));
    }
    if (lane == 0) { smx[w] = mx; smn[w] = mn; }
    __syncthreads();
    if (t == 0) {
        mx = fmaxf(fmaxf(smx[0], smx[1]), fmaxf(smx[2], smx[3]));
        mn = fminf(fminf(smn[0], smn[1]), fminf(smn[2], smn[3]));
        float M = fmaxf(mx, 1e-12f);                  // diagonal clamp floor
        float r = 1.0f / M;
        float li2 = 2.0f / (r + r);                   // harmonic mean of [M,M] * 2
        float m = fminf(mn, 1e12f);
        float linter = fminf(fmaxf(5.0f - m, 0.0f), 1e6f);
        out[0] = li2 + linter;                        // ALPHA = BETA = 1
    }
}

extern "C" void kernel_launch(void* const* d_in, const int* in_sizes, int n_in,
                              void* d_out, int out_size, void* d_ws, size_t ws_size,
                              hipStream_t stream) {
    const float* x       = (const float*)d_in[0];
    const int*   labels  = (const int*)d_in[1];
    const float* centers = (const float*)d_in[2];
    float*        ws     = (float*)d_ws;
    float*        out    = (float*)d_out;

    k_main<<<NBLK, 256, 0, stream>>>(x, labels, centers, ws);
    k_final<<<1, 256, 0, stream>>>(ws, out);
}

// Round 11
// 94.773 us; speedup vs baseline: 5.8770x; 5.8770x over previous
//
#include <hip/hip_runtime.h>
#include <math.h>

#define BATCH 8192
#define FEAT  256
#define NCLS  1000

#define NGEMM   528                  // upper-tri 32x32 grid of 32x32 tiles, FIRST
#define REPL    2                    // replicas per class, same-XCD pairing
#define NINTRA  (REPL*NCLS)          // 2000 intra blocks
#define NBLK    (NGEMM + NINTRA)     // 2528
#define ROWCAP  16                   // rows staged in LDS per class
#define MEMCAP  96                   // hard cap on class size

// ws (f32): every block writes ws[blockIdx.x] (plain store, unique slot,
// unconditional -> harness 0xAA poison harmless).
//   [0,528)      per-GEMM-block min
//   [528,2528)   per-intra-block max

// LDS union:
//   GEMM : As[32][34] 4352 | Bs[32][34] 4352 | cmagI[32] | cmagJ[32] =  8960 B
//   intra: rowS[16][256] 16384 | mem[96] 384 | magS[96] 384          = 17152 B
__global__ __launch_bounds__(256) void k_main(const float* __restrict__ x,
                                              const int* __restrict__ labels,
                                              const float* __restrict__ centers,
                                              float* __restrict__ ws) {
    __shared__ __align__(16) char raw[17152];
    __shared__ float wred[4];
    __shared__ int cnt;
    int t = threadIdx.x;
    int lane = t & 63, w = t >> 6;

    if (blockIdx.x < NGEMM) {
        // ------- inter: upper-tri 32x32 tile, k-major LDS, 2x2 reg tile -------
        float (*As)[34] = reinterpret_cast<float(*)[34]>(raw);
        float (*Bs)[34] = reinterpret_cast<float(*)[34]>(raw + 4352);
        float* cmagI    = reinterpret_cast<float*>(raw + 8704);
        float* cmagJ    = reinterpret_cast<float*>(raw + 8832);

        int bi = 0, rem = blockIdx.x;               // unrank upper-tri 32x32 grid
        while (rem >= 32 - bi) { rem -= 32 - bi; ++bi; }
        int bj = bi + rem;
        int i0 = bi * 32, j0 = bj * 32;

        // cmag for both row-ranges (bit-exact rownorm tree, I/J interleaved)
        for (int q = w; q < 32; q += 4) {
            int gi = i0 + q, gj = j0 + q;
            float sI = 0.0f, sJ = 0.0f;
            if (gi < NCLS) {
                float4 v = reinterpret_cast<const float4*>(centers + (size_t)gi * FEAT)[lane];
                sI = v.x * v.x + v.y * v.y + v.z * v.z + v.w * v.w;
            }
            if (gj < NCLS) {
                float4 v = reinterpret_cast<const float4*>(centers + (size_t)gj * FEAT)[lane];
                sJ = v.x * v.x + v.y * v.y + v.z * v.z + v.w * v.w;
            }
            #pragma unroll
            for (int o = 32; o > 0; o >>= 1) {
                sI += __shfl_xor(sI, o);
                sJ += __shfl_xor(sJ, o);
            }
            if (lane == 0) { cmagI[q] = 2.0f * sI; cmagJ[q] = 2.0f * sJ; }
        }
        // (k-loop barriers below order cmag writes before the epilogue reads)

        int tx = t & 15, ty = t >> 4;               // 2 cols, 2 rows per thread
        float acc[2][2] = {{0.f, 0.f}, {0.f, 0.f}};
        for (int kk = 0; kk < FEAT; kk += 32) {
            {   // stage 32 rows x 32 k of A and B, k-major (2-way write conflict = free)
                int row = t >> 3, q = t & 7;
                int col = kk + q * 4;
                int gi = i0 + row, gj = j0 + row;
                float4 av = (gi < NCLS)
                    ? *reinterpret_cast<const float4*>(centers + (size_t)gi * FEAT + col)
                    : make_float4(0.f, 0.f, 0.f, 0.f);
                float4 bv = (gj < NCLS)
                    ? *reinterpret_cast<const float4*>(centers + (size_t)gj * FEAT + col)
                    : make_float4(0.f, 0.f, 0.f, 0.f);
                As[q * 4 + 0][row] = av.x; As[q * 4 + 1][row] = av.y;
                As[q * 4 + 2][row] = av.z; As[q * 4 + 3][row] = av.w;
                Bs[q * 4 + 0][row] = bv.x; Bs[q * 4 + 1][row] = bv.y;
                Bs[q * 4 + 2][row] = bv.z; Bs[q * 4 + 3][row] = bv.w;
            }
            __syncthreads();
            #pragma unroll
            for (int k = 0; k < 32; ++k) {          // k strictly sequential per acc
                float2 a2 = *reinterpret_cast<float2*>(&As[k][ty * 2]);
                float2 b2 = *reinterpret_cast<float2*>(&Bs[k][tx * 2]);
                acc[0][0] += a2.x * b2.x; acc[0][1] += a2.x * b2.y;
                acc[1][0] += a2.y * b2.x; acc[1][1] += a2.y * b2.y;
            }
            __syncthreads();
        }
        float lmin = 1e30f;
        #pragma unroll
        for (int jj = 0; jj < 2; ++jj) {
            int J = j0 + tx * 2 + jj;
            #pragma unroll
            for (int ii = 0; ii < 2; ++ii) {
                int I = i0 + ty * 2 + ii;
                if (I < NCLS && J < NCLS) {
                    float v1 = cmagJ[tx * 2 + jj] - 2.0f * acc[ii][jj];   // entry (I,J)
                    v1 = fminf(fmaxf(v1, 1e-12f), 1e12f);
                    float v2 = cmagI[ty * 2 + ii] - 2.0f * acc[ii][jj];   // entry (J,I)
                    v2 = fminf(fmaxf(v2, 1e-12f), 1e12f);
                    lmin = fminf(lmin, fminf(v1, v2));
                }
            }
        }
        #pragma unroll
        for (int o = 32; o > 0; o >>= 1) lmin = fminf(lmin, __shfl_xor(lmin, o));
        if (lane == 0) wred[w] = lmin;
        __syncthreads();
        if (t == 0) {
            float m = fminf(fminf(wred[0], wred[1]), fminf(wred[2], wred[3]));
            ws[blockIdx.x] = m;                         // plain store, unique slot
        }
    } else {
        // ---- intra: class-owned replicas; blocks 528+c and 1528+c share an XCD ----
        int bid = blockIdx.x - NGEMM;
        int c   = (bid < NCLS) ? bid : bid - NCLS;   // class id
        int r   = (bid < NCLS) ? 0 : 1;              // replica id
        float (*rowS)[256] = reinterpret_cast<float(*)[256]>(raw);
        int*   mem  = reinterpret_cast<int*>(raw + 16384);
        float* magS = reinterpret_cast<float*>(raw + 16768);

        if (t == 0) cnt = 0;
        __syncthreads();
        // find members: coalesced int4 scan of labels (L2-resident, 32KB)
        const int4* gl4 = reinterpret_cast<const int4*>(labels);
        #pragma unroll
        for (int k = 0; k < 8; ++k) {
            int4 lv = gl4[t + (k << 8)];
            int base = (t + (k << 8)) << 2;
            if (lv.x == c) { int p = atomicAdd(&cnt, 1); if (p < MEMCAP) mem[p] = base;     }
            if (lv.y == c) { int p = atomicAdd(&cnt, 1); if (p < MEMCAP) mem[p] = base + 1; }
            if (lv.z == c) { int p = atomicAdd(&cnt, 1); if (p < MEMCAP) mem[p] = base + 2; }
            if (lv.w == c) { int p = atomicAdd(&cnt, 1); if (p < MEMCAP) mem[p] = base + 3; }
        }
        __syncthreads();
        int n = cnt < MEMCAP ? cnt : MEMCAP;
        float vmax = 0.0f;
        if (n >= 2) {
            const float4* x4 = reinterpret_cast<const float4*>(x);
            // stage rows + tree mags, two rows in flight (named scalars, no arrays)
            for (int m = w; m < n; m += 8) {
                int m2 = m + 4;
                bool has2 = (m2 < n);
                float4 v0 = x4[(size_t)mem[m] * 64 + lane];
                float4 v1 = has2 ? x4[(size_t)mem[m2] * 64 + lane]
                                 : make_float4(0.f, 0.f, 0.f, 0.f);
                if (m < ROWCAP)
                    *reinterpret_cast<float4*>(&rowS[m][lane << 2]) = v0;
                if (has2 && m2 < ROWCAP)
                    *reinterpret_cast<float4*>(&rowS[m2][lane << 2]) = v1;
                float s0 = v0.x * v0.x + v0.y * v0.y + v0.z * v0.z + v0.w * v0.w;
                float s1 = v1.x * v1.x + v1.y * v1.y + v1.z * v1.z + v1.w * v1.w;
                #pragma unroll
                for (int o = 32; o > 0; o >>= 1) {   // independent trees, interleaved
                    s0 += __shfl_xor(s0, o);
                    s1 += __shfl_xor(s1, o);
                }
                if (lane == 0) {
                    magS[m] = s0;
                    if (has2) magS[m2] = s1;
                }
            }
            __syncthreads();
            int npairs = n * (n - 1) / 2;
            for (int p = r * 4 + w; p < npairs; p += 8) {    // residue-unique pairs
                int a = 0, rem = p;                           // unrank (a-major)
                while (rem >= n - 1 - a) { rem -= n - 1 - a; ++a; }
                int b = a + 1 + rem;
                float4 va = (a < ROWCAP)
                    ? *reinterpret_cast<float4*>(&rowS[a][lane << 2])
                    : x4[(size_t)mem[a] * 64 + lane];
                float4 vb = (b < ROWCAP)
                    ? *reinterpret_cast<float4*>(&rowS[b][lane << 2])
                    : x4[(size_t)mem[b] * 64 + lane];
                float s = va.x * vb.x + va.y * vb.y + va.z * vb.z + va.w * vb.w;
                #pragma unroll
                for (int o = 32; o > 0; o >>= 1) s += __shfl_xor(s, o);
                float d2 = magS[a] + magS[b] - 2.0f * s;     // add commutes: bit-same
                float d  = sqrtf(fmaxf(d2, 0.0f));
                d = fminf(fmaxf(d, 1e-12f), 1e12f);
                vmax = fmaxf(vmax, d);
            }
        }
        if (lane == 0) wred[w] = vmax;
        __syncthreads();
        if (t == 0) {
            float m = fmaxf(fmaxf(wred[0], wred[1]), fmaxf(wred[2], wred[3]));
            ws[blockIdx.x] = m;                         // plain store, unique slot
        }
    }
}

// One block, 256 threads: reduce the per-block partials, write the scalar.
__global__ __launch_bounds__(256) void k_final(const float* __restrict__ ws,
                                               float* __restrict__ out) {
    __shared__ float smx[4], smn[4];
    int t = threadIdx.x, lane = t & 63, w = t >> 6;
    float mn = 1e30f, mx = 0.0f;
    for (int i = t; i < NGEMM; i += 256)  mn = fminf(mn, ws[i]);
    for (int i = t; i < NINTRA; i += 256) mx = fmaxf(mx, ws[NGEMM + i]);
    #pragma unroll
    for (int o = 32; o > 0; o >>= 1) {
        mx = fmaxf(mx, __shfl_xor(mx, o));
        mn = fminf(mn, __shfl_xor(mn, o));
    }
    if (lane == 0) { smx[w] = mx; smn[w] = mn; }
    __syncthreads();
    if (t == 0) {
        mx = fmaxf(fmaxf(smx[0], smx[1]), fmaxf(smx[2], smx[3]));
        mn = fminf(fminf(smn[0], smn[1]), fminf(smn[2], smn[3]));
        float M = fmaxf(mx, 1e-12f);                  // diagonal clamp floor
        float r = 1.0f / M;
        float li2 = 2.0f / (r + r);                   // harmonic mean of [M,M] * 2
        float m = fminf(mn, 1e12f);
        float linter = fminf(fmaxf(5.0f - m, 0.0f), 1e6f);
        out[0] = li2 + linter;                        // ALPHA = BETA = 1
    }
}

extern "C" void kernel_launch(void* const* d_in, const int* in_sizes, int n_in,
                              void* d_out, int out_size, void* d_ws, size_t ws_size,
                              hipStream_t stream) {
    const float* x       = (const float*)d_in[0];
    const int*   labels  = (const int*)d_in[1];
    const float* centers = (const float*)d_in[2];
    float*        ws     = (float*)d_ws;
    float*        out    = (float*)d_out;

    k_main<<<NBLK, 256, 0, stream>>>(x, labels, centers, ws);
    k_final<<<1, 256, 0, stream>>>(ws, out);
}